// Round 2
// baseline (112.781 us; speedup 1.0000x reference)
//
#include <hip/hip_runtime.h>
#include <hip/hip_bf16.h>

typedef __attribute__((ext_vector_type(8))) short bf16x8;
typedef __attribute__((ext_vector_type(4))) float f32x4;
typedef __attribute__((ext_vector_type(2))) float f32x2;
typedef unsigned int uint32;
typedef __attribute__((ext_vector_type(4))) uint32 u32x4;

__device__ __forceinline__ unsigned short f2bf(float f) {
    unsigned int u = __float_as_uint(f);
    u = (u + 0x7FFFu + ((u >> 16) & 1u)) >> 16;
    return (unsigned short)u;
}

__device__ __forceinline__ uint32 cvt_pk_bf16(float lo, float hi) {
    uint32 r;
    asm("v_cvt_pk_bf16_f32 %0, %1, %2" : "=v"(r) : "v"(lo), "v"(hi));
    return r;
}

// x: (8,128,64,64) fp32 NCHW -> xt: (8,64,64,128) bf16 NHWC
__global__ __launch_bounds__(256) void transpose_x(const float* __restrict__ x,
                                                   unsigned short* __restrict__ xt) {
    __shared__ float tile[32][33];
    int bi = blockIdx.x;
    int wb = bi & 1, cb = (bi >> 1) & 3, y = (bi >> 3) & 63, b = bi >> 9;
    int t = threadIdx.x;
    int lw = t & 31, lc = t >> 5;
    #pragma unroll
    for (int pass = 0; pass < 4; ++pass) {
        int c = cb * 32 + lc + pass * 8;
        tile[lc + pass * 8][lw] = x[(((size_t)b * 128 + c) * 64 + y) * 64 + wb * 32 + lw];
    }
    __syncthreads();
    int cc = t & 31, xl = t >> 5;
    #pragma unroll
    for (int pass = 0; pass < 4; ++pass) {
        int xll = xl + pass * 8;
        xt[(((size_t)b * 64 + y) * 64 + wb * 32 + xll) * 128 + cb * 32 + cc] =
            f2bf(tile[cc][xll]);
    }
}

// weight: (128F,128C,3,3) fp32 -> wT: [k][f][c] bf16
__global__ __launch_bounds__(256) void prep_w(const float* __restrict__ w,
                                              unsigned short* __restrict__ wT) {
    int idx = blockIdx.x * 256 + threadIdx.x;
    if (idx >= 9 * 128 * 128) return;
    int k = idx >> 14;
    int rem = idx & 16383;
    int f = rem >> 7, c = rem & 127;
    wT[idx] = f2bf(w[((size_t)f * 128 + c) * 9 + k]);
}

// One block = one (b,ho) row. 4 independent waves, each 128F x 16 pixels.
// No inter-wave communication after the prologue barrier.
__global__ __launch_bounds__(256, 2) void dcn_main(
    const float* __restrict__ offset, const float* __restrict__ mask,
    const unsigned short* __restrict__ xt, const unsigned short* __restrict__ wT,
    float* __restrict__ out)
{
    __shared__ float pw_l[4][9][16][4];  // per-wave: corner weights*mask*valid
    __shared__ int   po_l[4][9][16][4];  // per-wave: corner byte offsets into xt row-plane

    int bi = blockIdx.x;
    int nb = (bi & 7) * 64 + (bi >> 3);  // XCD swizzle: batch -> one XCD
    int b = nb >> 6, ho = nb & 63;
    int t = threadIdx.x, lane = t & 63, wid = t >> 6;

    // ---- prologue: sampling params for this wave's 16 pixels x 9 taps ----
    #pragma unroll
    for (int it = 0; it < 3; ++it) {
        int item = it * 64 + lane;
        if (item < 144) {
            int k = item >> 4, p = item & 15;
            int wo = wid * 16 + p;
            int ki = k / 3, kj = k - ki * 3;
            float dy = offset[(((size_t)b * 18 + 2 * k)     * 64 + ho) * 64 + wo];
            float dx = offset[(((size_t)b * 18 + 2 * k + 1) * 64 + ho) * 64 + wo];
            float m  = mask  [(((size_t)b * 9  + k)         * 64 + ho) * 64 + wo];
            float py = (float)(ho - 1 + ki) + dy;
            float px = (float)(wo - 1 + kj) + dx;
            float y0f = floorf(py), x0f = floorf(px);
            float ly = py - y0f, lx = px - x0f;
            float hy = 1.f - ly, hx = 1.f - lx;
            int y0 = (int)y0f, x0 = (int)x0f;
            int y1 = y0 + 1, x1 = x0 + 1;
            float vy0 = (y0 >= 0 && y0 < 64) ? 1.f : 0.f;
            float vy1 = (y1 >= 0 && y1 < 64) ? 1.f : 0.f;
            float vx0 = (x0 >= 0 && x0 < 64) ? 1.f : 0.f;
            float vx1 = (x1 >= 0 && x1 < 64) ? 1.f : 0.f;
            pw_l[wid][k][p][0] = hy * hx * m * vy0 * vx0;
            pw_l[wid][k][p][1] = hy * lx * m * vy0 * vx1;
            pw_l[wid][k][p][2] = ly * hx * m * vy1 * vx0;
            pw_l[wid][k][p][3] = ly * lx * m * vy1 * vx1;
            int y0c = min(max(y0, 0), 63), y1c = min(max(y1, 0), 63);
            int x0c = min(max(x0, 0), 63), x1c = min(max(x1, 0), 63);
            po_l[wid][k][p][0] = (y0c * 64 + x0c) * 256;  // 256 B per (y,x) pixel row
            po_l[wid][k][p][1] = (y0c * 64 + x1c) * 256;
            po_l[wid][k][p][2] = (y1c * 64 + x0c) * 256;
            po_l[wid][k][p][3] = (y1c * 64 + x1c) * 256;
        }
    }
    __syncthreads();

    const char* xb = (const char*)xt + (size_t)b * 64 * 64 * 256;
    int p  = lane & 15;   // pixel within wave tile (also A-row lane, B-col lane)
    int lu = lane >> 4;   // k-chunk lane

    u32x4 g[4][4];        // [corner][ks-chunk] gather registers

    auto issue_tap = [&](int k) {
        const int* po = po_l[wid][k][p];
        int o0 = po[0], o1 = po[1], o2 = po[2], o3 = po[3];
        int co = lu * 16;
        #pragma unroll
        for (int ch = 0; ch < 4; ++ch) {
            g[0][ch] = *(const u32x4*)(xb + o0 + ch * 64 + co);
            g[1][ch] = *(const u32x4*)(xb + o1 + ch * 64 + co);
            g[2][ch] = *(const u32x4*)(xb + o2 + ch * 64 + co);
            g[3][ch] = *(const u32x4*)(xb + o3 + ch * 64 + co);
        }
    };

    f32x4 acc[8];
    #pragma unroll
    for (int i = 0; i < 8; ++i) acc[i] = (f32x4){0.f, 0.f, 0.f, 0.f};

    issue_tap(0);

    for (int k = 0; k < 9; ++k) {
        // ---- interp: consume g -> B-fragments (registers only, no LDS) ----
        const float* pwp = pw_l[wid][k][p];
        float w0 = pwp[0], w1 = pwp[1], w2 = pwp[2], w3 = pwp[3];
        bf16x8 bfr[4];
        #pragma unroll
        for (int ch = 0; ch < 4; ++ch) {
            uint32 r[4];
            #pragma unroll
            for (int i = 0; i < 4; ++i) {
                f32x2 a, s;
                uint32 u = g[0][ch][i];
                a.x = __uint_as_float(u << 16);
                a.y = __uint_as_float(u & 0xffff0000u);
                s = a * w0;
                u = g[1][ch][i];
                a.x = __uint_as_float(u << 16);
                a.y = __uint_as_float(u & 0xffff0000u);
                s += a * w1;
                u = g[2][ch][i];
                a.x = __uint_as_float(u << 16);
                a.y = __uint_as_float(u & 0xffff0000u);
                s += a * w2;
                u = g[3][ch][i];
                a.x = __uint_as_float(u << 16);
                a.y = __uint_as_float(u & 0xffff0000u);
                s += a * w3;
                r[i] = cvt_pk_bf16(s.x, s.y);
            }
            u32x4 rr = {r[0], r[1], r[2], r[3]};
            bfr[ch] = __builtin_bit_cast(bf16x8, rr);
        }

        // ---- issue next tap's gathers; they fly during A-loads + MFMA ----
        if (k < 8) issue_tap(k + 1);

        // ---- MFMA: 128F x 16pix, K=128 for this tap ----
        const unsigned short* wTk = wT + k * 16384;
        #pragma unroll
        for (int ks = 0; ks < 4; ++ks) {
            int cbase = ks * 32 + lu * 8;
            #pragma unroll
            for (int ft = 0; ft < 8; ++ft) {
                bf16x8 a = *(const bf16x8*)(wTk + (ft * 16 + p) * 128 + cbase);
                acc[ft] = __builtin_amdgcn_mfma_f32_16x16x32_bf16(a, bfr[ks], acc[ft], 0, 0, 0);
            }
        }
    }

    // ---- epilogue: D col = pixel (lane&15), row = (lane>>4)*4 + r ----
    float* outb = out + (size_t)b * 128 * 4096 + ho * 64 + wid * 16;
    #pragma unroll
    for (int ft = 0; ft < 8; ++ft)
        #pragma unroll
        for (int r = 0; r < 4; ++r) {
            int f = ft * 16 + lu * 4 + r;
            outb[(size_t)f * 4096 + p] = acc[ft][r];
        }
}

extern "C" void kernel_launch(void* const* d_in, const int* in_sizes, int n_in,
                              void* d_out, int out_size, void* d_ws, size_t ws_size,
                              hipStream_t stream) {
    const float* x      = (const float*)d_in[0];
    const float* offset = (const float*)d_in[1];
    const float* mask   = (const float*)d_in[2];
    const float* weight = (const float*)d_in[3];
    float* out = (float*)d_out;

    unsigned short* xt = (unsigned short*)d_ws;                 // 8 MiB
    unsigned short* wT = xt + (size_t)8 * 64 * 64 * 128;        // 288 KiB
    if (ws_size < (size_t)(8 * 64 * 64 * 128 + 9 * 128 * 128) * 2) return;

    transpose_x<<<4096, 256, 0, stream>>>(x, xt);
    prep_w<<<576, 256, 0, stream>>>(weight, wT);
    dcn_main<<<512, 256, 0, stream>>>(offset, mask, xt, wT, out);
}

// Round 3
// 56.426 us; speedup vs baseline: 1.9987x; 1.9987x over previous
//
#include <hip/hip_runtime.h>
#include <hip/hip_bf16.h>

typedef __attribute__((ext_vector_type(8))) short bf16x8;
typedef __attribute__((ext_vector_type(4))) float f32x4;
typedef __attribute__((ext_vector_type(2))) float f32x2;
typedef unsigned int uint32;
typedef unsigned short ushort_t;
typedef __attribute__((ext_vector_type(4))) uint32 u32x4;

__device__ __forceinline__ ushort_t f2bf(float f) {
    unsigned int u = __float_as_uint(f);
    u = (u + 0x7FFFu + ((u >> 16) & 1u)) >> 16;
    return (ushort_t)u;
}

__device__ __forceinline__ uint32 cvt_pk_bf16(float lo, float hi) {
    uint32 r;
    asm("v_cvt_pk_bf16_f32 %0, %1, %2" : "=v"(r) : "v"(lo), "v"(hi));
    return r;
}

__device__ __forceinline__ void gload_lds16(const void* g, void* l) {
    __builtin_amdgcn_global_load_lds(
        (const __attribute__((address_space(1))) uint32*)g,
        (__attribute__((address_space(3))) uint32*)l, 16, 0, 0);
}

// x: (8,128,64,64) fp32 NCHW -> xt: (8,64,64,128) bf16 NHWC.
// blockIdx low bits = batch, so each batch's xt is written (and later read)
// on the same XCD (round-robin dispatch heuristic).
__global__ __launch_bounds__(256) void transpose_x(const float* __restrict__ x,
                                                   unsigned short* __restrict__ xt) {
    __shared__ float tile[32][33];
    int bi = blockIdx.x;
    int b = bi & 7;
    int r2 = bi >> 3;
    int wb = r2 & 1, cb = (r2 >> 1) & 3, y = r2 >> 3;
    int t = threadIdx.x;
    int lw = t & 31, lc = t >> 5;
    #pragma unroll
    for (int pass = 0; pass < 4; ++pass) {
        int c = cb * 32 + lc + pass * 8;
        tile[lc + pass * 8][lw] = x[(((size_t)b * 128 + c) * 64 + y) * 64 + wb * 32 + lw];
    }
    __syncthreads();
    int cc = t & 31, xl = t >> 5;
    #pragma unroll
    for (int pass = 0; pass < 4; ++pass) {
        int xll = xl + pass * 8;
        xt[(((size_t)b * 64 + y) * 64 + wb * 32 + xll) * 128 + cb * 32 + cc] =
            f2bf(tile[cc][xll]);
    }
}

// weight (128F,128C,3,3) fp32 -> wT2[tap][ks][lu][f][j] bf16 (fragment-major):
// element (tap, f, c=ks*32+lu*8+j) at index (((tap*4+ks)*4+lu)*128+f)*8+j.
__global__ __launch_bounds__(256) void prep_w(const float* __restrict__ w,
                                              ushort_t* __restrict__ wT2) {
    int idx = blockIdx.x * 256 + threadIdx.x;
    if (idx >= 9 * 16384) return;
    int tap = idx >> 14;
    int rem = idx & 16383;
    int j = rem & 7, f = (rem >> 3) & 127, lu = (rem >> 10) & 3, ks = rem >> 12;
    int c = ks * 32 + lu * 8 + j;
    wT2[idx] = f2bf(w[((size_t)f * 128 + c) * 9 + tap]);
}

// Block = 512 thr (8 waves) = 64 pixels x 128 F of one (b,ho) row.
// Waves: pg = pixel group (16 pix), tg = tap group (taps 0-3 / 4-8).
// A staged in LDS per tap; B gathered+interp'd into registers; K-split
// partial accs reduced through LDS at the end.
__global__ __launch_bounds__(512, 4) void dcn_main(
    const float* __restrict__ offset, const float* __restrict__ mask,
    const ushort_t* __restrict__ xt, const ushort_t* __restrict__ wT2,
    float* __restrict__ out)
{
    __shared__ ushort_t Abuf[2][16384];        // 64 KB: A tiles for tg0/tg1
    __shared__ float    pws[8][5][16][4];      // 10 KB: corner weights*mask*valid
    __shared__ ushort_t pos[8][5][16][4];      // 5 KB: corner pixel idx (y*64+x)

    int bi = blockIdx.x;
    int b = bi & 7, ho = bi >> 3;              // batch <-> XCD
    int t = threadIdx.x, lane = t & 63, wid = t >> 6;
    int tg = wid >> 2, pg = wid & 3;
    int p = lane & 15, lu = lane >> 4;
    int nt = tg ? 5 : 4, t0 = tg ? 4 : 0;

    // ---- prologue: per-wave sampling params (own region, no races) ----
    for (int item = lane; item < nt * 16; item += 64) {
        int tl = item >> 4, pi = item & 15;
        int k = t0 + tl;
        int wo = pg * 16 + pi;
        int ki = k / 3, kj = k - ki * 3;
        float dy = offset[(((size_t)b * 18 + 2 * k)     * 64 + ho) * 64 + wo];
        float dx = offset[(((size_t)b * 18 + 2 * k + 1) * 64 + ho) * 64 + wo];
        float m  = mask  [(((size_t)b * 9  + k)         * 64 + ho) * 64 + wo];
        float py = (float)(ho - 1 + ki) + dy;
        float px = (float)(wo - 1 + kj) + dx;
        float y0f = floorf(py), x0f = floorf(px);
        float ly = py - y0f, lx = px - x0f;
        float hy = 1.f - ly, hx = 1.f - lx;
        int y0 = (int)y0f, x0 = (int)x0f;
        int y1 = y0 + 1, x1 = x0 + 1;
        float vy0 = (y0 >= 0 && y0 < 64) ? 1.f : 0.f;
        float vy1 = (y1 >= 0 && y1 < 64) ? 1.f : 0.f;
        float vx0 = (x0 >= 0 && x0 < 64) ? 1.f : 0.f;
        float vx1 = (x1 >= 0 && x1 < 64) ? 1.f : 0.f;
        pws[wid][tl][pi][0] = hy * hx * m * vy0 * vx0;
        pws[wid][tl][pi][1] = hy * lx * m * vy0 * vx1;
        pws[wid][tl][pi][2] = ly * hx * m * vy1 * vx0;
        pws[wid][tl][pi][3] = ly * lx * m * vy1 * vx1;
        int y0c = min(max(y0, 0), 63), y1c = min(max(y1, 0), 63);
        int x0c = min(max(x0, 0), 63), x1c = min(max(x1, 0), 63);
        pos[wid][tl][pi][0] = (ushort_t)(y0c * 64 + x0c);
        pos[wid][tl][pi][1] = (ushort_t)(y0c * 64 + x1c);
        pos[wid][tl][pi][2] = (ushort_t)(y1c * 64 + x0c);
        pos[wid][tl][pi][3] = (ushort_t)(y1c * 64 + x1c);
    }

    const char* xb = (const char*)xt + (size_t)b * (64 * 64 * 256);
    f32x4 acc[8];
    #pragma unroll
    for (int i = 0; i < 8; ++i) acc[i] = (f32x4){0.f, 0.f, 0.f, 0.f};

    for (int s = 0; s < 5; ++s) {
        __syncthreads();  // previous MFMA done reading Abuf
        bool active = (tg == 1) || (s < 4);
        int o0 = 0, o1 = 0, o2 = 0, o3 = 0;
        float w0 = 0, w1 = 0, w2 = 0, w3 = 0;
        u32x4 gA[4][2];
        if (active) {
            o0 = (int)pos[wid][s][p][0] << 8;
            o1 = (int)pos[wid][s][p][1] << 8;
            o2 = (int)pos[wid][s][p][2] << 8;
            o3 = (int)pos[wid][s][p][3] << 8;
            w0 = pws[wid][s][p][0]; w1 = pws[wid][s][p][1];
            w2 = pws[wid][s][p][2]; w3 = pws[wid][s][p][3];
            #pragma unroll
            for (int h = 0; h < 2; ++h) {      // chunks 0,1 (channels 0..63)
                int co = h * 64 + lu * 16;
                gA[0][h] = *(const u32x4*)(xb + o0 + co);
                gA[1][h] = *(const u32x4*)(xb + o1 + co);
                gA[2][h] = *(const u32x4*)(xb + o2 + co);
                gA[3][h] = *(const u32x4*)(xb + o3 + co);
            }
        }
        // stage A tiles (linear LDS dest, fragment-major source)
        if (s < 4) {
            const ushort_t* src = wT2 + s * 16384;
            #pragma unroll
            for (int r = 0; r < 4; ++r) {
                int off = (r * 512 + t) * 8;
                gload_lds16(src + off, &Abuf[0][off]);
            }
        }
        {
            const ushort_t* src = wT2 + (4 + s) * 16384;
            #pragma unroll
            for (int r = 0; r < 4; ++r) {
                int off = (r * 512 + t) * 8;
                gload_lds16(src + off, &Abuf[1][off]);
            }
        }
        bf16x8 bfr[4];
        if (active) {
            #pragma unroll
            for (int h = 0; h < 2; ++h) {      // interp chunks 0,1
                uint32 rr[4];
                #pragma unroll
                for (int i = 0; i < 4; ++i) {
                    f32x2 a, sm;
                    uint32 u = gA[0][h][i];
                    a.x = __uint_as_float(u << 16); a.y = __uint_as_float(u & 0xffff0000u);
                    sm = a * w0;
                    u = gA[1][h][i];
                    a.x = __uint_as_float(u << 16); a.y = __uint_as_float(u & 0xffff0000u);
                    sm += a * w1;
                    u = gA[2][h][i];
                    a.x = __uint_as_float(u << 16); a.y = __uint_as_float(u & 0xffff0000u);
                    sm += a * w2;
                    u = gA[3][h][i];
                    a.x = __uint_as_float(u << 16); a.y = __uint_as_float(u & 0xffff0000u);
                    sm += a * w3;
                    rr[i] = cvt_pk_bf16(sm.x, sm.y);
                }
                u32x4 q = {rr[0], rr[1], rr[2], rr[3]};
                bfr[h] = __builtin_bit_cast(bf16x8, q);
            }
            u32x4 gB[4][2];
            #pragma unroll
            for (int h = 0; h < 2; ++h) {      // chunks 2,3 (channels 64..127)
                int co = (2 + h) * 64 + lu * 16;
                gB[0][h] = *(const u32x4*)(xb + o0 + co);
                gB[1][h] = *(const u32x4*)(xb + o1 + co);
                gB[2][h] = *(const u32x4*)(xb + o2 + co);
                gB[3][h] = *(const u32x4*)(xb + o3 + co);
            }
            #pragma unroll
            for (int h = 0; h < 2; ++h) {
                uint32 rr[4];
                #pragma unroll
                for (int i = 0; i < 4; ++i) {
                    f32x2 a, sm;
                    uint32 u = gB[0][h][i];
                    a.x = __uint_as_float(u << 16); a.y = __uint_as_float(u & 0xffff0000u);
                    sm = a * w0;
                    u = gB[1][h][i];
                    a.x = __uint_as_float(u << 16); a.y = __uint_as_float(u & 0xffff0000u);
                    sm += a * w1;
                    u = gB[2][h][i];
                    a.x = __uint_as_float(u << 16); a.y = __uint_as_float(u & 0xffff0000u);
                    sm += a * w2;
                    u = gB[3][h][i];
                    a.x = __uint_as_float(u << 16); a.y = __uint_as_float(u & 0xffff0000u);
                    sm += a * w3;
                    rr[i] = cvt_pk_bf16(sm.x, sm.y);
                }
                u32x4 q = {rr[0], rr[1], rr[2], rr[3]};
                bfr[2 + h] = __builtin_bit_cast(bf16x8, q);
            }
        }
        __syncthreads();  // stage visible
        if (active) {
            const ushort_t* At = &Abuf[tg][0];
            #pragma unroll
            for (int ks = 0; ks < 4; ++ks) {
                #pragma unroll
                for (int ft = 0; ft < 8; ++ft) {
                    bf16x8 a = *(const bf16x8*)&At[((ks * 4 + lu) * 128 + ft * 16 + p) * 8];
                    acc[ft] = __builtin_amdgcn_mfma_f32_16x16x32_bf16(a, bfr[ks], acc[ft], 0, 0, 0);
                }
            }
        }
    }

    // ---- epilogue: cross-tap-group reduction via LDS (reuses Abuf[0]) ----
    __syncthreads();
    float* red = (float*)&Abuf[0][0];  // [8 regions: (half*4+pg)][64 fl][16 p]
    if (tg == 1) {
        #pragma unroll
        for (int ft = 0; ft < 4; ++ft)
            #pragma unroll
            for (int r = 0; r < 4; ++r) {
                int fl = ft * 16 + lu * 4 + r;
                red[((0 + pg) * 64 + fl) * 16 + p] = acc[ft][r];
            }
    } else {
        #pragma unroll
        for (int ft = 4; ft < 8; ++ft)
            #pragma unroll
            for (int r = 0; r < 4; ++r) {
                int fl = (ft - 4) * 16 + lu * 4 + r;
                red[((4 + pg) * 64 + fl) * 16 + p] = acc[ft][r];
            }
    }
    __syncthreads();
    float* outb = out + (size_t)b * 128 * 4096 + ho * 64 + pg * 16 + p;
    if (tg == 0) {
        #pragma unroll
        for (int ft = 0; ft < 4; ++ft)
            #pragma unroll
            for (int r = 0; r < 4; ++r) {
                int fl = ft * 16 + lu * 4 + r;
                outb[(size_t)fl * 4096] = acc[ft][r] + red[((0 + pg) * 64 + fl) * 16 + p];
            }
    } else {
        #pragma unroll
        for (int ft = 4; ft < 8; ++ft)
            #pragma unroll
            for (int r = 0; r < 4; ++r) {
                int fl = (ft - 4) * 16 + lu * 4 + r;
                outb[(size_t)(64 + fl) * 4096] = acc[ft][r] + red[((4 + pg) * 64 + fl) * 16 + p];
            }
    }
}

extern "C" void kernel_launch(void* const* d_in, const int* in_sizes, int n_in,
                              void* d_out, int out_size, void* d_ws, size_t ws_size,
                              hipStream_t stream) {
    const float* x      = (const float*)d_in[0];
    const float* offset = (const float*)d_in[1];
    const float* mask   = (const float*)d_in[2];
    const float* weight = (const float*)d_in[3];
    float* out = (float*)d_out;

    ushort_t* xt  = (ushort_t*)d_ws;                       // 8 MiB
    ushort_t* wT2 = xt + (size_t)8 * 64 * 64 * 128;        // 288 KiB
    if (ws_size < (size_t)(8 * 64 * 64 * 128 + 9 * 16384) * 2) return;

    transpose_x<<<4096, 256, 0, stream>>>(x, xt);
    prep_w<<<576, 256, 0, stream>>>(weight, wT2);
    dcn_main<<<512, 512, 0, stream>>>(offset, mask, xt, wT2, out);
}